// Round 6
// baseline (686.499 us; speedup 1.0000x reference)
//
#include <hip/hip_runtime.h>
#include <hip/hip_bf16.h>

#define BB 8
#define NN 16384
#define CC 128
#define MM 256
#define NS 32
#define FPS_T 1024
#define PPT (NN / FPS_T)   // 16 points per thread

// Output layout (flat f32, concatenated in return order):
//   grouped_p [B,3,M,NS]  = 196608   @ 0
//   center_p  [B,M,3]     = 6144     @ 196608
//   fj        [B,C,M,NS]  = 8388608  @ 202752
//   center_x  [B,C,M,1]   = 262144   @ 8591360
#define OFF_GP  0
#define OFF_CP  196608
#define OFF_FJ  202752
#define OFF_CX  8591360

// ---------------- FPS: one block per batch ----------------------------------
// Exact numpy-f32 arithmetic: __f*_rn intrinsics block FMA contraction;
// distances >= 0 so float bit-pattern order == value order; key = bits<<32|~n
// gives argmax with smallest-index tiebreak as a single u64 max.
//
// R2-R4 lesson: no source-level hint (launch_bounds min-waves, asm pin,
// waves_per_eu(4,4)) stops the backend from sinking the point loads into the
// 255-iteration loop (VGPR stuck at 48-52; L1 re-stream 196KB/CU/iter ~= 3072
// cy/iter, matching the measured 4170 cy/iter). Fix: stage x,y in 128 KB LDS
// (compiler can't sink LDS-staged data; ds_read_b64 is conflict-free at
// consecutive addresses). z stays in 16 asm-pinned VGPRs; dist is loop-carried
// (unsinkable). 128 KB LDS also forces 1 block/CU = 4 waves/EU structurally,
// aligning the allocator's occupancy model with a 128-VGPR budget.
__global__ __launch_bounds__(FPS_T)
__attribute__((amdgpu_waves_per_eu(4, 4)))
void fps_kernel(const float* __restrict__ p, int* __restrict__ idx_out)
{
    __shared__ float s_xy[NN * 2];                 // 128 KB: x,y interleaved
    __shared__ unsigned long long s_key[2][16];    // double-buffered candidates

    const int b = blockIdx.x;
    const int t = threadIdx.x;
    const int lane = t & 63;
    const float* pb = p + (size_t)b * NN * 3;

    float pz[PPT], dist[PPT];
#pragma unroll
    for (int k = 0; k < PPT; ++k) {
        const int n = t + k * FPS_T;
        s_xy[2 * n + 0] = pb[n * 3 + 0];
        s_xy[2 * n + 1] = pb[n * 3 + 1];
        pz[k] = pb[n * 3 + 2];
        dist[k] = 1e10f;
    }
    // z must not be re-loaded from global inside the i-loop.
#pragma unroll
    for (int k = 0; k < PPT; ++k) {
        asm volatile("" : "+v"(pz[k]));
    }

    float cx = pb[0], cy = pb[1], cz = pb[2];
    if (t == 0) idx_out[b * MM + 0] = 0;
    __syncthreads();   // s_xy visible to all waves

    for (int i = 1; i < MM; ++i) {
        float bv = -1.0f;
#pragma unroll
        for (int k = 0; k < PPT; ++k) {
            const int n = t + k * FPS_T;
            const float2 xy = *(const float2*)&s_xy[2 * n];   // ds_read_b64
            // exact numpy order: ((dx*dx + dy*dy) + dz*dz)
            const float dx = __fsub_rn(xy.x, cx);
            const float dy = __fsub_rn(xy.y, cy);
            const float dz = __fsub_rn(pz[k], cz);
            const float d = __fadd_rn(
                __fadd_rn(__fmul_rn(dx, dx), __fmul_rn(dy, dy)),
                __fmul_rn(dz, dz));
            const float nd = fminf(dist[k], d);
            dist[k] = nd;
            bv = fmaxf(bv, nd);
        }
        // post-pass argmax: descending k, == match -> smallest k wins
        // (cndmask with inline-constant k; bn computed once after).
        int kb = 0;
#pragma unroll
        for (int k = PPT - 1; k >= 0; --k) {
            if (dist[k] == bv) kb = k;
        }
        const int bn = t + (kb << 10);
        unsigned long long key =
            ((unsigned long long)__float_as_uint(bv) << 32) |
            (unsigned int)(~bn);
        // 64-lane butterfly: every lane ends with the wave max key
#pragma unroll
        for (int off = 32; off > 0; off >>= 1) {
            const unsigned long long ok = __shfl_xor(key, off);
            if (ok > key) key = ok;
        }
        const int buf = i & 1;
        if (lane == 0) s_key[buf][t >> 6] = key;
        __syncthreads();
        // cross-wave reduce, lane-parallel: 16-lane group butterflies the
        // 16 wave keys to the block max.
        unsigned long long fk = s_key[buf][lane & 15];
#pragma unroll
        for (int off = 8; off > 0; off >>= 1) {
            const unsigned long long ok = __shfl_xor(fk, off);
            if (ok > fk) fk = ok;
        }
        const int fn = __builtin_amdgcn_readfirstlane(~((unsigned int)fk));
        // scalar-uniform broadcast load of the new center (constant-cache)
        cx = pb[fn * 3 + 0];
        cy = pb[fn * 3 + 1];
        cz = pb[fn * 3 + 2];
        if (t == 0) idx_out[b * MM + i] = fn;
        // no second barrier: next iter writes s_key[buf^1]; writes to
        // s_key[buf] recur only after the NEXT barrier, which orders them
        // after every wave's reads above.
    }
}

// ---------------- Ball query: one wave per center, 128 pts/iter -------------
__global__ __launch_bounds__(64) void ballq_kernel(
    const float* __restrict__ p, const int* __restrict__ idx,
    int* __restrict__ nidx, float* __restrict__ grouped_p,
    float* __restrict__ center_p)
{
    const int bm = blockIdx.x;
    const int b = bm >> 8;
    const int m = bm & 255;
    const int lane = threadIdx.x;
    const float* pb = p + (size_t)b * NN * 3;

    const int cidx = idx[bm];
    const float cx = pb[cidx * 3 + 0];
    const float cy = pb[cidx * 3 + 1];
    const float cz = pb[cidx * 3 + 2];

    if (lane < 3) {
        center_p[bm * 3 + lane] = (lane == 0) ? cx : (lane == 1) ? cy : cz;
    }

    // r2 must be f32(0.01) == 0x3C23D70A; 0.1f*0.1f rounds one ULP higher.
    const float R2 = 0.01f;

    __shared__ int lidx[NS];

    int found = 0;
    for (int base = 0; base < NN && found < NS; base += 128) {
        const int n0 = base + lane;
        const int n1 = base + 64 + lane;
        const float dx0 = __fsub_rn(pb[n0 * 3 + 0], cx);
        const float dy0 = __fsub_rn(pb[n0 * 3 + 1], cy);
        const float dz0 = __fsub_rn(pb[n0 * 3 + 2], cz);
        const float d20 = __fadd_rn(
            __fadd_rn(__fmul_rn(dx0, dx0), __fmul_rn(dy0, dy0)),
            __fmul_rn(dz0, dz0));
        const float dx1 = __fsub_rn(pb[n1 * 3 + 0], cx);
        const float dy1 = __fsub_rn(pb[n1 * 3 + 1], cy);
        const float dz1 = __fsub_rn(pb[n1 * 3 + 2], cz);
        const float d21 = __fadd_rn(
            __fadd_rn(__fmul_rn(dx1, dx1), __fmul_rn(dy1, dy1)),
            __fmul_rn(dz1, dz1));
        const bool w0 = d20 < R2;
        const bool w1 = d21 < R2;
        const unsigned long long m0 = __ballot(w0);
        const unsigned long long m1 = __ballot(w1);
        const int pc0 = (int)__popcll(m0);
        const unsigned long long below = (1ull << lane) - 1ull;
        const int slot0 = found + __popcll(m0 & below);
        const int slot1 = found + pc0 + __popcll(m1 & below);
        if (w0 && slot0 < NS) lidx[slot0] = n0;
        if (w1 && slot1 < NS) lidx[slot1] = n1;
        found += pc0 + (int)__popcll(m1);
    }
    __syncthreads();

    const int nfound = found < NS ? found : NS;
    if (lane < NS) {
        const int s = lane;
        const int n = (s < nfound) ? lidx[s] : lidx[0];
        nidx[bm * NS + s] = n;
        const float gx = __fsub_rn(pb[n * 3 + 0], cx);
        const float gy = __fsub_rn(pb[n * 3 + 1], cy);
        const float gz = __fsub_rn(pb[n * 3 + 2], cz);
        grouped_p[(((size_t)b * 3 + 0) * MM + m) * NS + s] = gx;
        grouped_p[(((size_t)b * 3 + 1) * MM + m) * NS + s] = gy;
        grouped_p[(((size_t)b * 3 + 2) * MM + m) * NS + s] = gz;
    }
}

// ---------------- fj gather: one block per (b,m) ----------------------------
__global__ __launch_bounds__(256) void fj_kernel(
    const float* __restrict__ x, const int* __restrict__ nidx,
    float* __restrict__ fj)
{
    const int bm = blockIdx.x;
    const int b = bm >> 8;
    const int m = bm & 255;

    __shared__ int lidx[NS];
    if (threadIdx.x < NS) lidx[threadIdx.x] = nidx[bm * NS + threadIdx.x];
    __syncthreads();

    const int s  = threadIdx.x & 31;
    const int c0 = threadIdx.x >> 5;   // 0..7
    const int n = lidx[s];
    const float* xb = x + (size_t)b * CC * NN;
    float* ob = fj + (size_t)b * CC * MM * NS + (size_t)m * NS + s;

#pragma unroll
    for (int c = c0; c < CC; c += 8) {
        ob[(size_t)c * MM * NS] = xb[(size_t)c * NN + n];
    }
}

// ---------------- center_x gather: one block per (b,c) ----------------------
__global__ __launch_bounds__(256) void cx_kernel(
    const float* __restrict__ x, const int* __restrict__ idx,
    float* __restrict__ center_x)
{
    const int bc = blockIdx.x;
    const int b = bc >> 7;
    const int m = threadIdx.x;
    const int n = idx[b * MM + m];
    center_x[(size_t)bc * MM + m] = x[(size_t)bc * NN + n];
}

extern "C" void kernel_launch(void* const* d_in, const int* in_sizes, int n_in,
                              void* d_out, int out_size, void* d_ws, size_t ws_size,
                              hipStream_t stream) {
    const float* p = (const float*)d_in[0];   // [8,16384,3]
    const float* x = (const float*)d_in[1];   // [8,128,16384]
    float* out = (float*)d_out;

    float* grouped_p = out + OFF_GP;
    float* center_p  = out + OFF_CP;
    float* fj        = out + OFF_FJ;
    float* center_x  = out + OFF_CX;

    int* idx  = (int*)d_ws;                   // [8,256]
    int* nidx = idx + BB * MM;                // [8,256,32]

    fps_kernel<<<BB, FPS_T, 0, stream>>>(p, idx);
    ballq_kernel<<<BB * MM, 64, 0, stream>>>(p, idx, nidx, grouped_p, center_p);
    fj_kernel<<<BB * MM, 256, 0, stream>>>(x, nidx, fj);
    cx_kernel<<<BB * CC, 256, 0, stream>>>(x, idx, center_x);
}